// Round 7
// baseline (97.709 us; speedup 1.0000x reference)
//
#include <hip/hip_runtime.h>
#include <hip/hip_bf16.h>

#define H 768
#define SEQ 256
#define NPAIR 32896                // S*(S+1)/2 = 257*128
#define NOUTP 160
#define OFF_H2H 263168u            // 4*32896*2
#define OFF_T2T 9737216u           // OFF_H2H + 4*24*32896*3

#define N_BPK 122880               // 24 k32-steps * 10 frags * 64 lanes * 8 bf16
#define N_FCW 1179648              // 1536*768
#define SCL 2.8853900817779268f    // 2*log2(e): pre-scale L/R so stage tanh needs no mul

typedef short bf16x8 __attribute__((ext_vector_type(8)));
typedef float f32x4 __attribute__((ext_vector_type(4)));

__device__ __forceinline__ float tanh_s(float xs) {
    // xs = 2*log2(e)*x  ->  tanh(x) = 1 - 2/(exp2(xs)+1)
    float e = __builtin_amdgcn_exp2f(xs);
    return fmaf(-2.0f, __builtin_amdgcn_rcpf(e + 1.0f), 1.0f);
}
__device__ __forceinline__ float bf_lo(int w){ return __uint_as_float(((unsigned)w) << 16); }
__device__ __forceinline__ float bf_hi(int w){ return __uint_as_float(((unsigned)w) & 0xffff0000u); }
__device__ __forceinline__ float bfu(unsigned short u){ return __uint_as_float(((unsigned)u) << 16); }
__device__ __forceinline__ int cvtpk(float lo, float hi) {
    int r;
    asm("v_cvt_pk_bf16_f32 %0, %1, %2" : "=v"(r) : "v"(lo), "v"(hi));
    return r;
}
__device__ __forceinline__ unsigned short bf16r(float x){
    unsigned int u = __float_as_uint(x);
    u += 0x7fffu + ((u >> 16) & 1u);
    return (unsigned short)(u >> 16);
}
__device__ __forceinline__ bf16x8 tanh_frag(int4 lv, int4 rv) {
    int4 st;
    st.x = cvtpk(tanh_s(bf_lo(lv.x) + bf_lo(rv.x)), tanh_s(bf_hi(lv.x) + bf_hi(rv.x)));
    st.y = cvtpk(tanh_s(bf_lo(lv.y) + bf_lo(rv.y)), tanh_s(bf_hi(lv.y) + bf_hi(rv.y)));
    st.z = cvtpk(tanh_s(bf_lo(lv.z) + bf_lo(rv.z)), tanh_s(bf_hi(lv.z) + bf_hi(rv.z)));
    st.w = cvtpk(tanh_s(bf_lo(lv.w) + bf_lo(rv.w)), tanh_s(bf_hi(lv.w) + bf_hi(rv.w)));
    return __builtin_bit_cast(bf16x8, st);
}

typedef const __attribute__((address_space(1))) unsigned int* as1_u32p;
typedef __attribute__((address_space(3))) unsigned int* as3_u32p;
__device__ __forceinline__ void gload_lds16(const void* g, void* l) {
    __builtin_amdgcn_global_load_lds((as1_u32p)g, (as3_u32p)l, 16, 0, 0);
}

__device__ __forceinline__ int row_start(int i) { return i * SEQ - (i * (i - 1)) / 2; }
__device__ __forceinline__ void pair_ij(int p, int& oi, int& oj) {
    double disc = 263169.0 - 8.0 * (double)p;   // (2S+1)^2 - 8p
    int i = (int)((513.0 - sqrt(disc)) * 0.5);
    if (i > 0 && row_start(i) > p) --i;
    while (row_start(i + 1) <= p) ++i;
    oi = i;
    oj = i + (p - row_start(i));
}

// ---------------- kernel 0: pack Bpk (fragment-ordered), fcwb, bc ----------------
__global__ __launch_bounds__(256) void pack_kernel(
    const float* __restrict__ h2t_w, const float* __restrict__ h2h_w,
    const float* __restrict__ t2t_w, const float* __restrict__ h2t_b,
    const float* __restrict__ h2h_b, const float* __restrict__ t2t_b,
    const float* __restrict__ fc_w,
    unsigned short* __restrict__ Bpk, unsigned short* __restrict__ fcwb,
    float* __restrict__ bc)
{
    int idx = blockIdx.x * 256 + threadIdx.x;
    if (idx < N_BPK) {
        int j = idx & 7, lane = (idx >> 3) & 63, rest = idx >> 9;
        int f = rest % 10, k32 = rest / 10;
        int n = f * 16 + (lane & 15);
        int k = k32 * 32 + ((lane >> 4) << 3) + j;
        float v = 0.f;
        if (n < 2)        v = h2t_w[n * H + k];
        else if (n < 74)  v = h2h_w[(n - 2) * H + k];
        else if (n < 146) v = t2t_w[(n - 74) * H + k];
        Bpk[idx] = bf16r(v);
    } else if (idx < N_BPK + N_FCW) {
        int q = idx - N_BPK;
        int n = q / H, k = q % H;
        float v = (n < H) ? fc_w[(size_t)n * 2 * H + k]
                          : fc_w[(size_t)(n - H) * 2 * H + H + k];
        fcwb[q] = bf16r(v);
    } else if (idx < N_BPK + N_FCW + NOUTP) {
        int q = idx - N_BPK - N_FCW;
        float v = 0.f;
        if (q < 2)        v = h2t_b[q];
        else if (q < 74)  v = h2h_b[q - 2];
        else if (q < 146) v = t2t_b[q - 74];
        bc[q] = v;
    }
}

// ---------------- kernel 1: LB/RB = hidden @ fc_w (bf16 MFMA GEMM), pre-scaled by SCL ----------------
__global__ __launch_bounds__(256, 2) void lr_mfma(
    const float* __restrict__ hidden, const unsigned short* __restrict__ fcwb,
    const float* __restrict__ fc_b,
    unsigned short* __restrict__ LB, unsigned short* __restrict__ RB)
{
    __shared__ __align__(16) char sm[24576];          // A 8KB | B 16KB
    const int tid = threadIdx.x, l = tid & 63, w = tid >> 6;
    const int wm = w >> 1, wn = w & 1;
    const int m0 = blockIdx.x * 64, n0 = blockIdx.y * 128;
    f32x4 acc[2][4] = {};
    for (int c = 0; c < 12; ++c) {
        const int k0 = c * 64;
        #pragma unroll
        for (int it = 0; it < 2; ++it) {              // A: 64 rows x 64 k, cvt f32->bf16
            int idx = tid + it * 256;
            int row = idx >> 3, k8 = idx & 7;
            const float4* src = reinterpret_cast<const float4*>(hidden + (size_t)(m0 + row) * H + k0 + k8 * 8);
            float4 a = src[0], bq = src[1];
            int4 st;
            st.x = cvtpk(a.x, a.y);  st.y = cvtpk(a.z, a.w);
            st.z = cvtpk(bq.x, bq.y); st.w = cvtpk(bq.z, bq.w);
            *reinterpret_cast<int4*>(sm + row * 128 + ((k8 * 16) ^ ((row & 7) << 4))) = st;
        }
        #pragma unroll
        for (int it = 0; it < 4; ++it) {              // B: 128 rows x 64 k
            int idx = tid + it * 256;
            int row = idx >> 3, k8 = idx & 7;
            *reinterpret_cast<int4*>(sm + 8192 + row * 128 + ((k8 * 16) ^ ((row & 7) << 4))) =
                *reinterpret_cast<const int4*>(fcwb + (size_t)(n0 + row) * H + k0 + k8 * 8);
        }
        __syncthreads();
        #pragma unroll
        for (int kk = 0; kk < 2; ++kk) {
            const int sl = kk * 4 + (l >> 4);
            const int swz = (l & 7) << 4;
            bf16x8 af[2], bfr[4];
            #pragma unroll
            for (int a = 0; a < 2; ++a) {
                int row = 32 * wm + 16 * a + (l & 15);
                af[a] = *reinterpret_cast<const bf16x8*>(sm + row * 128 + ((sl * 16) ^ swz));
            }
            #pragma unroll
            for (int f = 0; f < 4; ++f) {
                int row = 64 * wn + 16 * f + (l & 15);
                bfr[f] = *reinterpret_cast<const bf16x8*>(sm + 8192 + row * 128 + ((sl * 16) ^ swz));
            }
            #pragma unroll
            for (int a = 0; a < 2; ++a)
                #pragma unroll
                for (int f = 0; f < 4; ++f)
                    acc[a][f] = __builtin_amdgcn_mfma_f32_16x16x32_bf16(af[a], bfr[f], acc[a][f], 0, 0, 0);
        }
        __syncthreads();
    }
    #pragma unroll
    for (int a = 0; a < 2; ++a)
        #pragma unroll
        for (int f = 0; f < 4; ++f)
            #pragma unroll
            for (int r = 0; r < 4; ++r) {
                int row = m0 + 32 * wm + 16 * a + 4 * (l >> 4) + r;
                int col = n0 + 64 * wn + 16 * f + (l & 15);
                float v = acc[a][f][r];
                if (n0 < H) LB[(size_t)row * H + col] = bf16r((v + fc_b[col]) * SCL);
                else        RB[(size_t)row * H + (col - H)] = bf16r(v * SCL);
            }
}

// ---------------- kernel 2: A-in-regs, B via global_load_lds, counted-vmcnt barrier ----------------
// block = 256 thr (4 waves), wave = 32 rows x 160 cols (acc 2x10), M-tile = 128, chunk = 64 k
#define SLAB_STR 166   // bf16 slab stride: 83 words, gcd(83mod32=19,32)=1 -> conflict-free strided reads

__global__ __launch_bounds__(256, 3) void pair_mfma(
    const unsigned short* __restrict__ LB, const unsigned short* __restrict__ RB,
    const unsigned short* __restrict__ Bpk, const float* __restrict__ bc,
    float* __restrict__ out)
{
    __shared__ __align__(16) char sm[43136];
    // K-loop: B buf0 [0,20480) | buf1 [20480,40960) | iOf/jOf alias [0,1024) pre-staging | bc_s [42496,43136)
    // epilogue: bf16 slab [128][166] = 42496 B at [0,42496)
    int*   iOf  = reinterpret_cast<int*>(sm);
    int*   jOf  = reinterpret_cast<int*>(sm + 512);
    float* bc_s = reinterpret_cast<float*>(sm + 42496);

    const int tid = threadIdx.x, l = tid & 63, w = tid >> 6;
    const int b = blockIdx.y, p0 = blockIdx.x * 128;

    if (tid < 128) {
        int i, j; pair_ij(p0 + tid, i, j);
        iOf[tid] = i * H; jOf[tid] = j * H;
    }
    if (tid < NOUTP) bc_s[tid] = bc[tid];
    __syncthreads();

    const unsigned short* LBb = LB + (size_t)b * SEQ * H;
    const unsigned short* RBb = RB + (size_t)b * SEQ * H;
    const int row0 = 32 * w + (l & 15);           // m=0 row; m=1 row = row0+16
    const int kb = (l >> 4) << 3;                 // lane k-seg base (bf16 units)
    const unsigned short* lp0 = LBb + iOf[row0] + kb;
    const unsigned short* rp0 = RBb + jOf[row0] + kb;
    const unsigned short* lp1 = LBb + iOf[row0 + 16] + kb;
    const unsigned short* rp1 = RBb + jOf[row0 + 16] + kb;
    __syncthreads();   // all iOf/jOf reads done before B staging overwrites [0,1024)

    const char* bsrc = reinterpret_cast<const char*>(Bpk) + w * 5120 + l * 16;  // per-lane global src
    const int ldst_off = w * 5120;                                               // wave-uniform LDS dest

    f32x4 acc[2][10] = {};

    // prologue: B(0) -> buf0 via gload_lds; L/R(0) -> regs
    #pragma unroll
    for (int t = 0; t < 5; ++t) gload_lds16(bsrc + t * 1024, sm + ldst_off + t * 1024);
    __builtin_amdgcn_sched_barrier(0);
    int4 lA0 = *reinterpret_cast<const int4*>(lp0);
    int4 lA1 = *reinterpret_cast<const int4*>(lp0 + 32);
    int4 lB0 = *reinterpret_cast<const int4*>(lp1);
    int4 lB1 = *reinterpret_cast<const int4*>(lp1 + 32);
    int4 rA0 = *reinterpret_cast<const int4*>(rp0);
    int4 rA1 = *reinterpret_cast<const int4*>(rp0 + 32);
    int4 rB0 = *reinterpret_cast<const int4*>(rp1);
    int4 rB1 = *reinterpret_cast<const int4*>(rp1 + 32);
    asm volatile("s_waitcnt vmcnt(8) lgkmcnt(0)" ::: "memory");
    __builtin_amdgcn_s_barrier();
    __builtin_amdgcn_sched_barrier(0);

    #pragma unroll 2
    for (int c = 0; c < 11; ++c) {
        char* bufc = sm + ((c & 1) ? 20480 : 0);
        char* bufn = sm + (((c + 1) & 1) ? 20480 : 0);
        // phase 1: B(c+1) -> bufn (issued first: oldest outstanding -> drained by vmcnt(8))
        const char* bn = bsrc + (c + 1) * 20480;
        #pragma unroll
        for (int t = 0; t < 5; ++t) gload_lds16(bn + t * 1024, bufn + ldst_off + t * 1024);
        __builtin_amdgcn_sched_barrier(0);
        // phase 2: tanh current L/R -> A frags (compiler emits counted vmcnt for these regs)
        bf16x8 a00 = tanh_frag(lA0, rA0);
        bf16x8 a10 = tanh_frag(lB0, rB0);
        bf16x8 a01 = tanh_frag(lA1, rA1);
        bf16x8 a11 = tanh_frag(lB1, rB1);
        // phase 3: issue next-chunk L/R (newest outstanding: stay in flight across barrier)
        const int co = (c + 1) * 64;
        lA0 = *reinterpret_cast<const int4*>(lp0 + co);
        lA1 = *reinterpret_cast<const int4*>(lp0 + co + 32);
        lB0 = *reinterpret_cast<const int4*>(lp1 + co);
        lB1 = *reinterpret_cast<const int4*>(lp1 + co + 32);
        rA0 = *reinterpret_cast<const int4*>(rp0 + co);
        rA1 = *reinterpret_cast<const int4*>(rp0 + co + 32);
        rB0 = *reinterpret_cast<const int4*>(rp1 + co);
        rB1 = *reinterpret_cast<const int4*>(rp1 + co + 32);
        // phase 4: MFMA on bufc (B frags: contiguous per-lane 16B reads)
        #pragma unroll
        for (int f = 0; f < 10; ++f) {
            bf16x8 bf0 = *reinterpret_cast<const bf16x8*>(bufc + (f * 64 + l) * 16);
            acc[0][f] = __builtin_amdgcn_mfma_f32_16x16x32_bf16(a00, bf0, acc[0][f], 0, 0, 0);
            acc[1][f] = __builtin_amdgcn_mfma_f32_16x16x32_bf16(a10, bf0, acc[1][f], 0, 0, 0);
        }
        #pragma unroll
        for (int f = 0; f < 10; ++f) {
            bf16x8 bf1 = *reinterpret_cast<const bf16x8*>(bufc + ((10 + f) * 64 + l) * 16);
            acc[0][f] = __builtin_amdgcn_mfma_f32_16x16x32_bf16(a01, bf1, acc[0][f], 0, 0, 0);
            acc[1][f] = __builtin_amdgcn_mfma_f32_16x16x32_bf16(a11, bf1, acc[1][f], 0, 0, 0);
        }
        // phase 5: counted barrier — drain B(c+1) gload_lds (5), keep L/R (8) in flight
        asm volatile("s_waitcnt vmcnt(8) lgkmcnt(0)" ::: "memory");
        __builtin_amdgcn_s_barrier();
        __builtin_amdgcn_sched_barrier(0);
    }
    {   // peeled chunk 11 (no prefetch)
        bf16x8 a00 = tanh_frag(lA0, rA0);
        bf16x8 a10 = tanh_frag(lB0, rB0);
        bf16x8 a01 = tanh_frag(lA1, rA1);
        bf16x8 a11 = tanh_frag(lB1, rB1);
        const char* bufc = sm + 20480;          // 11&1 = 1
        #pragma unroll
        for (int f = 0; f < 10; ++f) {
            bf16x8 bf0 = *reinterpret_cast<const bf16x8*>(bufc + (f * 64 + l) * 16);
            acc[0][f] = __builtin_amdgcn_mfma_f32_16x16x32_bf16(a00, bf0, acc[0][f], 0, 0, 0);
            acc[1][f] = __builtin_amdgcn_mfma_f32_16x16x32_bf16(a10, bf0, acc[1][f], 0, 0, 0);
        }
        #pragma unroll
        for (int f = 0; f < 10; ++f) {
            bf16x8 bf1 = *reinterpret_cast<const bf16x8*>(bufc + ((10 + f) * 64 + l) * 16);
            acc[0][f] = __builtin_amdgcn_mfma_f32_16x16x32_bf16(a01, bf1, acc[0][f], 0, 0, 0);
            acc[1][f] = __builtin_amdgcn_mfma_f32_16x16x32_bf16(a11, bf1, acc[1][f], 0, 0, 0);
        }
    }
    asm volatile("s_waitcnt lgkmcnt(0)" ::: "memory");   // all LDS reads of buf1 retired
    __builtin_amdgcn_s_barrier();

    // epilogue: ONE shared bf16 slab [128][SLAB_STR], one barrier, fully parallel softmax
    unsigned short* slab = reinterpret_cast<unsigned short*>(sm);
    #pragma unroll
    for (int m = 0; m < 2; ++m)
        #pragma unroll
        for (int f = 0; f < 10; ++f)
            #pragma unroll
            for (int r = 0; r < 4; ++r) {
                int row = 32 * w + 16 * m + 4 * (l >> 4) + r;
                slab[row * SLAB_STR + f * 16 + (l & 15)] = bf16r(acc[m][f][r]);
            }
    __syncthreads();

    {   // h2t: 128 pairs x 2
        int p = tid >> 1, tt = tid & 1;
        float val = bfu(slab[p * SLAB_STR + tt]) + bc_s[tt];
        __builtin_nontemporal_store(val, &out[((size_t)b * NPAIR + p0 + p) * 2 + tt]);
    }
    #pragma unroll
    for (int it = 0; it < 24; ++it) {                    // 48 rr x 128 p, rr-major (coalesced stores)
        int item = it * 256 + tid;
        int p = item & 127, rr = item >> 7;
        int ob = 2 + rr * 3;
        const unsigned short* sp = slab + p * SLAB_STR + ob;
        float l0 = bfu(sp[0]) + bc_s[ob + 0];
        float l1 = bfu(sp[1]) + bc_s[ob + 1];
        float l2 = bfu(sp[2]) + bc_s[ob + 2];
        float mx = fmaxf(l0, fmaxf(l1, l2));
        float e0 = __expf(l0 - mx), e1 = __expf(l1 - mx), e2 = __expf(l2 - mx);
        float inv = __fdividef(1.0f, e0 + e1 + e2);
        size_t base = (rr < 24)
            ? (size_t)OFF_H2H + ((size_t)(b * 24 + rr) * NPAIR + p0 + p) * 3
            : (size_t)OFF_T2T + ((size_t)(b * 24 + rr - 24) * NPAIR + p0 + p) * 3;
        __builtin_nontemporal_store(e0 * inv, &out[base + 0]);
        __builtin_nontemporal_store(e1 * inv, &out[base + 1]);
        __builtin_nontemporal_store(e2 * inv, &out[base + 2]);
    }
}

extern "C" void kernel_launch(void* const* d_in, const int* in_sizes, int n_in,
                              void* d_out, int out_size, void* d_ws, size_t ws_size,
                              hipStream_t stream) {
    const float* hidden = (const float*)d_in[0];
    const float* fc_w   = (const float*)d_in[1];
    const float* fc_b   = (const float*)d_in[2];
    const float* h2t_w  = (const float*)d_in[3];
    const float* h2t_b  = (const float*)d_in[4];
    const float* h2h_w  = (const float*)d_in[5];
    const float* h2h_b  = (const float*)d_in[6];
    const float* t2t_w  = (const float*)d_in[7];
    const float* t2t_b  = (const float*)d_in[8];

    char* wsb = (char*)d_ws;
    unsigned short* LBw  = (unsigned short*)(wsb);              // 1024*768 bf16 = 1.5 MB
    unsigned short* RBw  = (unsigned short*)(wsb + 1572864);    // 1.5 MB
    unsigned short* Bpk  = (unsigned short*)(wsb + 3145728);    // 240 KB
    unsigned short* fcwb = (unsigned short*)(wsb + 3391488);    // 2.25 MB
    float*          bc   = (float*)        (wsb + 5750784);     // 640 B

    float* out = (float*)d_out;

    pack_kernel<<<(N_BPK + N_FCW + NOUTP + 255) / 256, 256, 0, stream>>>(
        h2t_w, h2h_w, t2t_w, h2t_b, h2h_b, t2t_b, fc_w, Bpk, fcwb, bc);
    lr_mfma<<<dim3(16, 12), 256, 0, stream>>>(hidden, fcwb, fc_b, LBw, RBw);
    pair_mfma<<<dim3(NPAIR / 128, 4), 256, 0, stream>>>(LBw, RBw, Bpk, bc, out);
}